// Round 9
// baseline (99.752 us; speedup 1.0000x reference)
//
#include <hip/hip_runtime.h>

// Problem constants (pinned by the reference)
#define UNITS     49152
#define INPUT_DIM 15
#define BATCH     2048

constexpr int TPB          = 256;
constexpr int U_PER_THREAD = 4;                       // float4 along U
constexpr int U_PER_BLOCK  = TPB * U_PER_THREAD;      // 1024
constexpr int COL_BLOCKS   = UNITS / U_PER_BLOCK;     // 48
constexpr int PHASES       = 32;                      // row phases (band height)
constexpr int NITER        = BATCH / PHASES;          // 64 rows per block
constexpr int NBLOCKS      = COL_BLOCKS * PHASES;     // 1536 (all co-resident)
constexpr int XS_STRIDE    = 16;                      // padded LDS row stride

typedef float f32x4 __attribute__((ext_vector_type(4)));

// One-time premask: mw[i][u] = w[i][u] * mask[u][i] (coalesced; ~2 us)
__global__ __launch_bounds__(256) void premask_kernel(
    const float* __restrict__ w,     // [INPUT_DIM, UNITS]
    const float* __restrict__ mask,  // [UNITS, INPUT_DIM]
    float* __restrict__ mw)          // [INPUT_DIM, UNITS]
{
    const int u = blockIdx.x * 256 + threadIdx.x;
    float m[INPUT_DIM];
#pragma unroll
    for (int i = 0; i < INPUT_DIM; ++i) m[i] = mask[(size_t)u * INPUT_DIM + i];
#pragma unroll
    for (int i = 0; i < INPUT_DIM; ++i)
        mw[(size_t)i * UNITS + u] = w[(size_t)i * UNITS + u] * m[i];
}

// Lockstep-v2: block(phase, colblk) writes rows {32k + phase}. All 1536
// blocks are co-resident with identical per-iteration work (LDS + VALU only,
// no global loads in the loop), so iterations stay in soft lockstep and the
// GPU-wide write front at step k is the contiguous 6 MB band rows [32k,32k+32).
// Only semantic change vs the 83us R2 kernel: row->block assignment.
template <bool PREMASKED>
__global__ __launch_bounds__(TPB) void striatum_kernel(
    const float* __restrict__ x,     // [BATCH, INPUT_DIM]
    const float* __restrict__ w,     // [INPUT_DIM, UNITS] (premasked if PREMASKED)
    const float* __restrict__ bias,  // [UNITS]
    const float* __restrict__ mask,  // [UNITS, INPUT_DIM] (unused if PREMASKED)
    float* __restrict__ out)         // [BATCH, UNITS]
{
    __shared__ __align__(16) float xs[NITER * XS_STRIDE];  // 64 rows x 16 = 4 KB

    const int b      = blockIdx.x;
    const int colblk = b % COL_BLOCKS;   // 0..47 fixed column slice
    const int phase  = b / COL_BLOCKS;   // 0..31 row phase within the band
    const int u0     = colblk * U_PER_BLOCK + threadIdx.x * U_PER_THREAD;

    // Stage this block's 64 strided rows (32k + phase) into padded LDS.
    for (int idx = threadIdx.x; idx < NITER * XS_STRIDE; idx += TPB) {
        const int j = idx >> 4, col = idx & 15;
        const int srcrow = j * PHASES + phase;
        xs[idx] = (col < INPUT_DIM) ? x[(size_t)srcrow * INPUT_DIM + col] : 0.0f;
    }

    // This thread's 4 fixed weight columns in registers (coalesced float4).
    f32x4 mw[INPUT_DIM];
#pragma unroll
    for (int i = 0; i < INPUT_DIM; ++i) {
        f32x4 wv = *reinterpret_cast<const f32x4*>(&w[(size_t)i * UNITS + u0]);
        if constexpr (!PREMASKED) {
            wv.x *= mask[(size_t)(u0 + 0) * INPUT_DIM + i];
            wv.y *= mask[(size_t)(u0 + 1) * INPUT_DIM + i];
            wv.z *= mask[(size_t)(u0 + 2) * INPUT_DIM + i];
            wv.w *= mask[(size_t)(u0 + 3) * INPUT_DIM + i];
        }
        mw[i] = wv;
    }
    const f32x4 bv = *reinterpret_cast<const f32x4*>(&bias[u0]);

    __syncthreads();

    const f32x4* xs4 = reinterpret_cast<const f32x4*>(xs);

    // Band sweep: iteration k writes row 32k + phase (GPU-wide rows [32k,32k+32)).
    for (int k = 0; k < NITER; ++k) {
        f32x4 xa[4];
#pragma unroll
        for (int j = 0; j < 4; ++j) xa[j] = xs4[k * 4 + j];   // 4x ds_read_b128
        const float v[16] = {xa[0].x, xa[0].y, xa[0].z, xa[0].w,
                             xa[1].x, xa[1].y, xa[1].z, xa[1].w,
                             xa[2].x, xa[2].y, xa[2].z, xa[2].w,
                             xa[3].x, xa[3].y, xa[3].z, xa[3].w};
        f32x4 acc = bv;
#pragma unroll
        for (int i = 0; i < INPUT_DIM; ++i) {
            acc.x = fmaf(v[i], mw[i].x, acc.x);
            acc.y = fmaf(v[i], mw[i].y, acc.y);
            acc.z = fmaf(v[i], mw[i].z, acc.z);
            acc.w = fmaf(v[i], mw[i].w, acc.w);
        }
        const int row = k * PHASES + phase;
        __builtin_nontemporal_store(acc,
            reinterpret_cast<f32x4*>(&out[(size_t)row * UNITS + u0]));
    }
}

extern "C" void kernel_launch(void* const* d_in, const int* in_sizes, int n_in,
                              void* d_out, int out_size, void* d_ws, size_t ws_size,
                              hipStream_t stream) {
    const float* x    = (const float*)d_in[0];  // inputs [2048, 15]
    const float* w    = (const float*)d_in[1];  // w      [15, 49152]
    const float* b    = (const float*)d_in[2];  // b      [49152]
    const float* mask = (const float*)d_in[3];  // mask   [49152, 15]
    float* out        = (float*)d_out;          // [2048, 49152]

    const size_t mw_bytes = (size_t)INPUT_DIM * UNITS * sizeof(float);  // 2.95 MB

    if (ws_size >= mw_bytes) {
        float* mw = (float*)d_ws;
        premask_kernel<<<UNITS / 256, 256, 0, stream>>>(w, mask, mw);
        striatum_kernel<true><<<NBLOCKS, TPB, 0, stream>>>(x, mw, b, mask, out);
    } else {
        striatum_kernel<false><<<NBLOCKS, TPB, 0, stream>>>(x, w, b, mask, out);
    }
}

// Round 10
// 97.173 us; speedup vs baseline: 1.0265x; 1.0265x over previous
//
#include <hip/hip_runtime.h>

// Problem constants (pinned by the reference)
#define UNITS     49152
#define INPUT_DIM 15
#define BATCH     2048

constexpr int TPB            = 256;
constexpr int U_PER_THREAD   = 4;                     // float4 along U
constexpr int U_PER_BLOCK    = TPB * U_PER_THREAD;    // 1024
constexpr int COL_BLOCKS     = UNITS / U_PER_BLOCK;   // 48
constexpr int ROWS_PER_BLOCK = 64;                    // batch rows per block
constexpr int ROW_GROUPS     = BATCH / ROWS_PER_BLOCK;// 32
constexpr int NBLOCKS        = COL_BLOCKS * ROW_GROUPS; // 1536

typedef float f32x4 __attribute__((ext_vector_type(4)));

// R6 kernel body verbatim (in-kernel masking, scalar LDS reads, PLAIN stores).
// ONLY change: 1D grid with bid = colblk*32 + rowgroup, so bid%8 == rowgroup%8
// -> every column-chunk of a rowgroup dispatches to the SAME XCD (round-robin
// heuristic, m09). Each 12 MB rowgroup region aggregates in one L2 and drains
// as contiguous full-row bursts instead of a 4KB-strided 8-XCD comb.
__global__ __launch_bounds__(TPB) void striatum_kernel(
    const float* __restrict__ x,     // [BATCH, INPUT_DIM]
    const float* __restrict__ w,     // [INPUT_DIM, UNITS]
    const float* __restrict__ bias,  // [UNITS]
    const float* __restrict__ mask,  // [UNITS, INPUT_DIM]
    float* __restrict__ out)         // [BATCH, UNITS]
{
    __shared__ float xs[ROWS_PER_BLOCK * INPUT_DIM];  // 960 floats = 3.84 KB

    const int colblk = blockIdx.x / ROW_GROUPS;       // 0..47 column slice
    const int rg     = blockIdx.x % ROW_GROUPS;       // 0..31 rowgroup -> XCD rg%8
    const int u0     = colblk * U_PER_BLOCK + threadIdx.x * U_PER_THREAD;
    const int row0   = rg * ROWS_PER_BLOCK;

    // Cooperative load of the x row-tile into LDS (960 elements over 256 threads)
    for (int idx = threadIdx.x; idx < ROWS_PER_BLOCK * INPUT_DIM; idx += TPB) {
        xs[idx] = x[row0 * INPUT_DIM + idx];
    }

    // Pre-mask this thread's 4 weight columns into registers.
    f32x4 mw[INPUT_DIM];
#pragma unroll
    for (int i = 0; i < INPUT_DIM; ++i) {
        f32x4 wv = *reinterpret_cast<const f32x4*>(&w[(size_t)i * UNITS + u0]);
        wv.x *= mask[(size_t)(u0 + 0) * INPUT_DIM + i];
        wv.y *= mask[(size_t)(u0 + 1) * INPUT_DIM + i];
        wv.z *= mask[(size_t)(u0 + 2) * INPUT_DIM + i];
        wv.w *= mask[(size_t)(u0 + 3) * INPUT_DIM + i];
        mw[i] = wv;
    }
    const f32x4 bv = *reinterpret_cast<const f32x4*>(&bias[u0]);

    __syncthreads();

    // Stream ROWS_PER_BLOCK output rows; weights stay in registers.
    for (int r = 0; r < ROWS_PER_BLOCK; ++r) {
        const float* xr = &xs[r * INPUT_DIM];   // broadcast reads (same addr all lanes)
        f32x4 acc = bv;
#pragma unroll
        for (int i = 0; i < INPUT_DIM; ++i) {
            const float xv = xr[i];
            acc.x = fmaf(xv, mw[i].x, acc.x);
            acc.y = fmaf(xv, mw[i].y, acc.y);
            acc.z = fmaf(xv, mw[i].z, acc.z);
            acc.w = fmaf(xv, mw[i].w, acc.w);
        }
        // Plain cached store: dirty lines aggregate in this rowgroup's single
        // XCD L2 and drain as long contiguous bursts.
        *reinterpret_cast<f32x4*>(&out[(size_t)(row0 + r) * UNITS + u0]) = acc;
    }
}

extern "C" void kernel_launch(void* const* d_in, const int* in_sizes, int n_in,
                              void* d_out, int out_size, void* d_ws, size_t ws_size,
                              hipStream_t stream) {
    const float* x    = (const float*)d_in[0];  // inputs [2048, 15]
    const float* w    = (const float*)d_in[1];  // w      [15, 49152]
    const float* b    = (const float*)d_in[2];  // b      [49152]
    const float* mask = (const float*)d_in[3];  // mask   [49152, 15]
    float* out        = (float*)d_out;          // [2048, 49152]

    striatum_kernel<<<NBLOCKS, TPB, 0, stream>>>(x, w, b, mask, out);
}